// Round 2
// baseline (2131.662 us; speedup 1.0000x reference)
//
#include <hip/hip_runtime.h>

namespace {

constexpr int QN = 4;
constexpr int MR = 8192;   // B*S
constexpr int DD = 768;
constexpr int HH = 512;
constexpr int NN = 1024;
constexpr float DELTA = 0.008f;   // argmax tie-recheck threshold (~10 sigma of bf16 gap error)

typedef __attribute__((ext_vector_type(8))) __bf16 bf16x8;
typedef __attribute__((ext_vector_type(4))) __bf16 bf16x4;
typedef __attribute__((ext_vector_type(4))) float  f32x4;

#define GL2LDS(g, l) __builtin_amdgcn_global_load_lds( \
    (const __attribute__((address_space(1))) void*)(g), \
    (__attribute__((address_space(3))) void*)(l), 16, 0, 0)

// ------------- transpose + fp32->bf16 weight conversion -----------------
// src: [batch][K][N] fp32  ->  dst: [batch][N][K] bf16
__global__ __launch_bounds__(256)
void wcvt(const float* __restrict__ src, __bf16* __restrict__ dst, int K, int N)
{
    __shared__ float tile[32][33];
    const size_t bo = (size_t)blockIdx.z * K * N;
    const int n0 = blockIdx.x * 32, k0 = blockIdx.y * 32;
    const int tx = threadIdx.x, ty = threadIdx.y;   // 32 x 8
    #pragma unroll
    for (int i = 0; i < 4; ++i)
        tile[ty + 8 * i][tx] = src[bo + (size_t)(k0 + ty + 8 * i) * N + n0 + tx];
    __syncthreads();
    #pragma unroll
    for (int i = 0; i < 4; ++i)
        dst[bo + (size_t)(n0 + ty + 8 * i) * K + k0 + tx] = (__bf16)tile[tx][ty + 8 * i];
}

// ------------- fp32 -> bf16 row-major copy (for x) ----------------------
__global__ __launch_bounds__(256)
void acvt(const float* __restrict__ src, __bf16* __restrict__ dst)
{
    const size_t i = ((size_t)blockIdx.x * 256 + threadIdx.x) * 8;
    float4 a = *(const float4*)(src + i);
    float4 b = *(const float4*)(src + i + 4);
    bf16x8 o;
    o[0] = (__bf16)a.x; o[1] = (__bf16)a.y; o[2] = (__bf16)a.z; o[3] = (__bf16)a.w;
    o[4] = (__bf16)b.x; o[5] = (__bf16)b.y; o[6] = (__bf16)b.z; o[7] = (__bf16)b.w;
    *(bf16x8*)(dst + i) = o;
}

// ------------- MFMA GEMM + BN(eval) + ReLU ------------------------------
// C[M,N] = relu(bn(A[M,K] @ B[K,N] + bias));  A bf16 [M][K], BT bf16 [N][K]
// 128x128 tile, BK=32, 256 threads (4 waves 2x2), 16x16x32 bf16 MFMA.
// OUTBF=1 -> bf16 out, OUTBF=0 -> fp32 out.
template<int OUTBF>
__global__ __launch_bounds__(256)
void gemm_mfma(const __bf16* __restrict__ A, const __bf16* __restrict__ BT,
               const float* __restrict__ bias, const float* __restrict__ gam,
               const float* __restrict__ beta, const float* __restrict__ mean,
               const float* __restrict__ var,
               float* __restrict__ C32, __bf16* __restrict__ Cbf,
               int N_, int K_)
{
    __shared__ __bf16 smem[8192];          // As 4096 | Bs 4096 (16 KB)
    __bf16* As = smem;
    __bf16* Bs = smem + 4096;

    const int t   = threadIdx.x;
    const int bn0 = blockIdx.x * 128;
    const int bm0 = blockIdx.y * 128;
    const int l    = t & 63, w = t >> 6;
    const int lm   = l & 15, quad = l >> 4;
    const int mrow = (w & 1) * 64, ncol = (w >> 1) * 64;

    // staging chunk decode: slot s holds (m = s>>2, q = ((s&3) - (m>>1)) & 3)
    const int sA0 = t, sA1 = t + 256;
    const int mA0 = sA0 >> 2, qA0 = ((sA0 & 3) - (mA0 >> 1)) & 3;
    const int mA1 = sA1 >> 2, qA1 = ((sA1 & 3) - (mA1 >> 1)) & 3;
    const size_t gA0 = (size_t)(bm0 + mA0) * K_ + qA0 * 8;
    const size_t gA1 = (size_t)(bm0 + mA1) * K_ + qA1 * 8;
    const size_t gB0 = (size_t)(bn0 + mA0) * K_ + qA0 * 8;
    const size_t gB1 = (size_t)(bn0 + mA1) * K_ + qA1 * 8;

    f32x4 acc[4][4] = {};

    // fragment LDS slots: slot(m,quad) = m*4 + ((quad + (m>>1)) & 3)
    int aslot[4], bslot[4];
    #pragma unroll
    for (int i = 0; i < 4; ++i) {
        int m = mrow + i * 16 + lm;
        aslot[i] = m * 4 + ((quad + (m >> 1)) & 3);
        int n = ncol + i * 16 + lm;
        bslot[i] = n * 4 + ((quad + (n >> 1)) & 3);
    }

    for (int k0 = 0; k0 < K_; k0 += 32) {
        GL2LDS(A  + gA0 + k0, As + sA0 * 8);
        GL2LDS(A  + gA1 + k0, As + sA1 * 8);
        GL2LDS(BT + gB0 + k0, Bs + sA0 * 8);
        GL2LDS(BT + gB1 + k0, Bs + sA1 * 8);
        asm volatile("s_waitcnt vmcnt(0)" ::: "memory");
        __syncthreads();

        bf16x8 af[4], bfv[4];
        #pragma unroll
        for (int i = 0; i < 4; ++i) {
            af[i]  = *(const bf16x8*)(As + aslot[i] * 8);
            bfv[i] = *(const bf16x8*)(Bs + bslot[i] * 8);
        }
        #pragma unroll
        for (int mt = 0; mt < 4; ++mt)
            #pragma unroll
            for (int nt = 0; nt < 4; ++nt)
                acc[mt][nt] = __builtin_amdgcn_mfma_f32_16x16x32_bf16(
                    af[mt], bfv[nt], acc[mt][nt], 0, 0, 0);
        __syncthreads();
    }

    // epilogue: bn + relu; C/D layout col = lane&15, row = quad*4 + reg
    float sc[4], sh[4]; int cn[4];
    #pragma unroll
    for (int nt = 0; nt < 4; ++nt) {
        int c = bn0 + ncol + nt * 16 + lm;
        cn[nt] = c;
        float s = gam[c] * rsqrtf(var[c] + 1e-5f);
        sc[nt] = s;
        sh[nt] = (bias[c] - mean[c]) * s + beta[c];
    }
    #pragma unroll
    for (int mt = 0; mt < 4; ++mt) {
        int r0 = bm0 + mrow + mt * 16 + quad * 4;
        #pragma unroll
        for (int nt = 0; nt < 4; ++nt) {
            #pragma unroll
            for (int reg = 0; reg < 4; ++reg) {
                float v = fmaxf(0.f, fmaf(acc[mt][nt][reg], sc[nt], sh[nt]));
                size_t off = (size_t)(r0 + reg) * N_ + cn[nt];
                if (OUTBF) Cbf[off] = (__bf16)v;
                else       C32[off] = v;
            }
        }
    }
}

// ------------- fused per-row epilogue ----------------------------------
__global__ __launch_bounds__(256)
void row_fuse(const float* __restrict__ z, const float* __restrict__ gum,
              const float* __restrict__ cb, const float* __restrict__ Ain,
              float* __restrict__ res, float* __restrict__ qout,
              __bf16* __restrict__ res_bf, __bf16* __restrict__ qo_bf,
              float* __restrict__ ent, float* __restrict__ lat,
              float* __restrict__ idxf,
              const float* __restrict__ W1, const float* __restrict__ b1,
              const float* __restrict__ g1, const float* __restrict__ be1,
              const float* __restrict__ m1, const float* __restrict__ v1,
              const float* __restrict__ W2, const float* __restrict__ b2,
              const float* __restrict__ g2, const float* __restrict__ be2,
              const float* __restrict__ m2, const float* __restrict__ v2,
              int first, int last)
{
    __shared__ float sred[8];
    __shared__ int   sredi[4];
    __shared__ float stop1;
    __shared__ int   stop1i;
    __shared__ int   sflag;
    __shared__ int   sidx;
    __shared__ float rowbuf[768];
    __shared__ float hs[512];

    const int r   = blockIdx.x;
    const int t   = threadIdx.x;
    const int wid = t >> 6;
    const bool l0 = (t & 63) == 0;

    const float4 z4 = ((const float4*)(z   + (size_t)r * NN))[t];
    const float4 g4 = ((const float4*)(gum + (size_t)r * NN))[t];

    // ---- softmax stats
    float mx = fmaxf(fmaxf(z4.x, z4.y), fmaxf(z4.z, z4.w));
    #pragma unroll
    for (int o = 1; o < 64; o <<= 1) mx = fmaxf(mx, __shfl_xor(mx, o, 64));
    if (l0) sred[wid] = mx;
    __syncthreads();
    mx = fmaxf(fmaxf(sred[0], sred[1]), fmaxf(sred[2], sred[3]));

    float e0 = __expf(z4.x - mx), e1 = __expf(z4.y - mx);
    float e2 = __expf(z4.z - mx), e3 = __expf(z4.w - mx);
    float s = (e0 + e1) + (e2 + e3);
    #pragma unroll
    for (int o = 1; o < 64; o <<= 1) s += __shfl_xor(s, o, 64);
    if (l0) sred[4 + wid] = s;
    __syncthreads();
    s = (sred[4] + sred[5]) + (sred[6] + sred[7]);

    const float inv = 1.0f / s;
    const float q0 = e0 * inv, q1 = e1 * inv, q2 = e2 * inv, q3 = e3 * inv;

    float ep = q0 * __logf(q0 + 1e-10f) + q1 * __logf(q1 + 1e-10f)
             + q2 * __logf(q2 + 1e-10f) + q3 * __logf(q3 + 1e-10f);
    #pragma unroll
    for (int o = 1; o < 64; o <<= 1) ep += __shfl_xor(ep, o, 64);

    float4 l4;
    l4.x = q0 * __logf(q0 * 1024.f + 1e-10f);
    l4.y = q1 * __logf(q1 * 1024.f + 1e-10f);
    l4.z = q2 * __logf(q2 * 1024.f + 1e-10f);
    l4.w = q3 * __logf(q3 * 1024.f + 1e-10f);
    ((float4*)(lat + (size_t)r * NN))[t] = l4;

    // ---- argmax(z + g), top-1
    const float y0 = z4.x + g4.x, y1 = z4.y + g4.y;
    const float y2 = z4.z + g4.z, y3 = z4.w + g4.w;
    float bv = y0; int bi = t * 4;
    if (y1 > bv) { bv = y1; bi = t * 4 + 1; }
    if (y2 > bv) { bv = y2; bi = t * 4 + 2; }
    if (y3 > bv) { bv = y3; bi = t * 4 + 3; }
    #pragma unroll
    for (int o = 1; o < 64; o <<= 1) {
        float ov = __shfl_xor(bv, o, 64);
        int   oi = __shfl_xor(bi, o, 64);
        if (ov > bv || (ov == bv && oi < bi)) { bv = ov; bi = oi; }
    }
    __syncthreads();                    // all reads of sred[] done
    if (l0) { sred[wid] = ep; sred[4 + wid] = bv; sredi[wid] = bi; }
    __syncthreads();
    if (t == 0) {
        ent[r] = -((sred[0] + sred[1]) + (sred[2] + sred[3]));
        float bbv = sred[4]; int bbi = sredi[0];
        #pragma unroll
        for (int ww = 1; ww < 4; ++ww)
            if (sred[4 + ww] > bbv || (sred[4 + ww] == bbv && sredi[ww] < bbi)) {
                bbv = sred[4 + ww]; bbi = sredi[ww];
            }
        stop1 = bbv; stop1i = bbi; sidx = bbi;
    }
    __syncthreads();
    const float t1v = stop1;
    const int   t1i = stop1i;

    // ---- top-2 (excluding top-1 index) for tie detection
    float ex = -1e30f;
    if (t * 4 + 0 != t1i) ex = y0;
    if (t * 4 + 1 != t1i) ex = fmaxf(ex, y1);
    if (t * 4 + 2 != t1i) ex = fmaxf(ex, y2);
    if (t * 4 + 3 != t1i) ex = fmaxf(ex, y3);
    #pragma unroll
    for (int o = 1; o < 64; o <<= 1) ex = fmaxf(ex, __shfl_xor(ex, o, 64));
    __syncthreads();
    if (l0) sred[wid] = ex;
    __syncthreads();
    if (t == 0) {
        float t2 = fmaxf(fmaxf(sred[0], sred[1]), fmaxf(sred[2], sred[3]));
        sflag = (t1v - t2 < DELTA) ? 1 : 0;
    }
    __syncthreads();

    // ---- slow path: fp32 recompute of this row's z, exact argmax
    if (sflag) {
        if (t < 192)
            *(float4*)&rowbuf[t * 4] = *(const float4*)(Ain + (size_t)r * DD + t * 4);
        __syncthreads();
        for (int j = t; j < HH; j += 256) {
            float a = 0.f;
            #pragma unroll 8
            for (int k = 0; k < DD; ++k) a = fmaf(rowbuf[k], W1[(size_t)k * HH + j], a);
            a += b1[j];
            float scl = g1[j] * rsqrtf(v1[j] + 1e-5f);
            a = (a - m1[j]) * scl + be1[j];
            hs[j] = fmaxf(a, 0.f);
        }
        __syncthreads();
        float zc[4];
        #pragma unroll
        for (int cc = 0; cc < 4; ++cc) {
            int c = t * 4 + cc;
            float a = 0.f;
            #pragma unroll 8
            for (int j = 0; j < HH; ++j) a = fmaf(hs[j], W2[(size_t)j * NN + c], a);
            a += b2[c];
            float scl = g2[c] * rsqrtf(v2[c] + 1e-5f);
            a = (a - m2[c]) * scl + be2[c];
            zc[cc] = fmaxf(a, 0.f);
        }
        float u0 = zc[0] + g4.x, u1 = zc[1] + g4.y;
        float u2 = zc[2] + g4.z, u3 = zc[3] + g4.w;
        float cv = u0; int cidx = t * 4;
        if (u1 > cv) { cv = u1; cidx = t * 4 + 1; }
        if (u2 > cv) { cv = u2; cidx = t * 4 + 2; }
        if (u3 > cv) { cv = u3; cidx = t * 4 + 3; }
        #pragma unroll
        for (int o = 1; o < 64; o <<= 1) {
            float ov = __shfl_xor(cv, o, 64);
            int   oi = __shfl_xor(cidx, o, 64);
            if (ov > cv || (ov == cv && oi < cidx)) { cv = ov; cidx = oi; }
        }
        __syncthreads();
        if (l0) { sred[wid] = cv; sredi[wid] = cidx; }
        __syncthreads();
        if (t == 0) {
            float bbv = sred[0]; int bbi = sredi[0];
            #pragma unroll
            for (int ww = 1; ww < 4; ++ww)
                if (sred[ww] > bbv || (sred[ww] == bbv && sredi[ww] < bbi)) {
                    bbv = sred[ww]; bbi = sredi[ww];
                }
            sidx = bbi;
        }
        __syncthreads();
    }

    const int ci = sidx;
    if (t == 0) idxf[r] = (float)ci;

    // ---- gather + residual / quantized_out update (+ bf16 mirrors)
    if (t < 192) {
        float4 c4 = *(const float4*)(cb + (size_t)ci * DD + t * 4);
        float4 rv, qv;
        if (first) {
            float4 xv = *(const float4*)(Ain + (size_t)r * DD + t * 4);
            rv.x = xv.x - c4.x; rv.y = xv.y - c4.y;
            rv.z = xv.z - c4.z; rv.w = xv.w - c4.w;
            qv = c4;
        } else {
            rv = *(const float4*)(res  + (size_t)r * DD + t * 4);
            qv = *(const float4*)(qout + (size_t)r * DD + t * 4);
            rv.x -= c4.x; rv.y -= c4.y; rv.z -= c4.z; rv.w -= c4.w;
            qv.x += c4.x; qv.y += c4.y; qv.z += c4.z; qv.w += c4.w;
        }
        *(float4*)(res  + (size_t)r * DD + t * 4) = rv;
        *(float4*)(qout + (size_t)r * DD + t * 4) = qv;
        bf16x4 rb;
        rb[0] = (__bf16)rv.x; rb[1] = (__bf16)rv.y;
        rb[2] = (__bf16)rv.z; rb[3] = (__bf16)rv.w;
        *(bf16x4*)(res_bf + (size_t)r * DD + t * 4) = rb;
        if (last) {
            bf16x4 qb;
            qb[0] = (__bf16)qv.x; qb[1] = (__bf16)qv.y;
            qb[2] = (__bf16)qv.z; qb[3] = (__bf16)qv.w;
            *(bf16x4*)(qo_bf + (size_t)r * DD + t * 4) = qb;
        }
    }
}

} // namespace

extern "C" void kernel_launch(void* const* d_in, const int* in_sizes, int n_in,
                              void* d_out, int out_size, void* d_ws, size_t ws_size,
                              hipStream_t stream)
{
    const float* x    = (const float*)d_in[0];
    const float* cb   = (const float*)d_in[1];
    const float* pW1  = (const float*)d_in[2];
    const float* pb1  = (const float*)d_in[3];
    const float* pg1  = (const float*)d_in[4];
    const float* pbe1 = (const float*)d_in[5];
    const float* pm1  = (const float*)d_in[6];
    const float* pv1  = (const float*)d_in[7];
    const float* pW2  = (const float*)d_in[8];
    const float* pb2  = (const float*)d_in[9];
    const float* pg2  = (const float*)d_in[10];
    const float* pbe2 = (const float*)d_in[11];
    const float* pm2  = (const float*)d_in[12];
    const float* pv2  = (const float*)d_in[13];
    const float* dW1  = (const float*)d_in[14];
    const float* db1  = (const float*)d_in[15];
    const float* dg1  = (const float*)d_in[16];
    const float* dbe1 = (const float*)d_in[17];
    const float* dm1  = (const float*)d_in[18];
    const float* dv1  = (const float*)d_in[19];
    const float* dW2  = (const float*)d_in[20];
    const float* db2  = (const float*)d_in[21];
    const float* dg2  = (const float*)d_in[22];
    const float* dbe2 = (const float*)d_in[23];
    const float* dm2  = (const float*)d_in[24];
    const float* dv2  = (const float*)d_in[25];
    const float* gum  = (const float*)d_in[26];

    // output layout (floats): xhat | entropies | latent | indices | zs
    float* out  = (float*)d_out;
    float* xhat = out;
    float* ent  = xhat + (size_t)MR * DD;
    float* lat  = ent  + (size_t)QN * MR;
    float* idxf = lat  + (size_t)QN * MR * NN;
    float* zs   = idxf + (size_t)QN * MR;

    // workspace layout
    char* wp = (char*)d_ws;
    float*  res   = (float*)wp;                 wp += (size_t)MR * DD * 4;
    float*  qo    = (float*)wp;                 wp += (size_t)MR * DD * 4;
    __bf16* Abf   = (__bf16*)wp;                wp += (size_t)MR * DD * 2;
    __bf16* hbf   = (__bf16*)wp;                wp += (size_t)MR * HH * 2;
    __bf16* qobf  = (__bf16*)wp;                wp += (size_t)MR * DD * 2;
    __bf16* h1bf  = (__bf16*)wp;                wp += (size_t)MR * 2 * DD * 2;
    __bf16* w1t   = (__bf16*)wp;                wp += (size_t)QN * DD * HH * 2;
    __bf16* w2t   = (__bf16*)wp;                wp += (size_t)QN * HH * NN * 2;
    __bf16* dw1t  = (__bf16*)wp;                wp += (size_t)DD * 2 * DD * 2;
    __bf16* dw2t  = (__bf16*)wp;                wp += (size_t)2 * DD * DD * 2;

    dim3 b256(256), bwc(32, 8);

    // weight transpose+convert
    hipLaunchKernelGGL(wcvt, dim3(HH / 32, DD / 32, QN), bwc, 0, stream, pW1, w1t, DD, HH);
    hipLaunchKernelGGL(wcvt, dim3(NN / 32, HH / 32, QN), bwc, 0, stream, pW2, w2t, HH, NN);
    hipLaunchKernelGGL(wcvt, dim3(2 * DD / 32, DD / 32, 1), bwc, 0, stream, dW1, dw1t, DD, 2 * DD);
    hipLaunchKernelGGL(wcvt, dim3(DD / 32, 2 * DD / 32, 1), bwc, 0, stream, dW2, dw2t, 2 * DD, DD);
    // x -> bf16
    hipLaunchKernelGGL(acvt, dim3((size_t)MR * DD / (8 * 256)), b256, 0, stream, x, Abf);

    for (int i = 0; i < QN; ++i) {
        hipLaunchKernelGGL((gemm_mfma<1>), dim3(HH / 128, MR / 128), b256, 0, stream,
            Abf, w1t + (size_t)i * DD * HH,
            pb1 + i * HH, pg1 + i * HH, pbe1 + i * HH, pm1 + i * HH, pv1 + i * HH,
            (float*)nullptr, hbf, HH, DD);
        float* z_i = zs + (size_t)i * MR * NN;
        hipLaunchKernelGGL((gemm_mfma<0>), dim3(NN / 128, MR / 128), b256, 0, stream,
            hbf, w2t + (size_t)i * HH * NN,
            pb2 + i * NN, pg2 + i * NN, pbe2 + i * NN, pm2 + i * NN, pv2 + i * NN,
            z_i, (__bf16*)nullptr, NN, HH);
        const float* Ain = (i == 0) ? x : res;
        hipLaunchKernelGGL(row_fuse, dim3(MR), b256, 0, stream,
            z_i, gum + (size_t)i * MR * NN, cb + (size_t)i * NN * DD, Ain,
            res, qo, Abf, qobf,
            ent + (size_t)i * MR, lat + (size_t)i * MR * NN, idxf + (size_t)i * MR,
            pW1 + (size_t)i * DD * HH, pb1 + i * HH, pg1 + i * HH, pbe1 + i * HH,
            pm1 + i * HH, pv1 + i * HH,
            pW2 + (size_t)i * HH * NN, pb2 + i * NN, pg2 + i * NN, pbe2 + i * NN,
            pm2 + i * NN, pv2 + i * NN,
            (int)(i == 0), (int)(i == QN - 1));
    }
    // decoder
    hipLaunchKernelGGL((gemm_mfma<1>), dim3(2 * DD / 128, MR / 128), b256, 0, stream,
        qobf, dw1t, db1, dg1, dbe1, dm1, dv1, (float*)nullptr, h1bf, 2 * DD, DD);
    hipLaunchKernelGGL((gemm_mfma<0>), dim3(DD / 128, MR / 128), b256, 0, stream,
        h1bf, dw2t, db2, dg2, dbe2, dm2, dv2, xhat, (__bf16*)nullptr, DD, 2 * DD);
}

// Round 3
// 1300.990 us; speedup vs baseline: 1.6385x; 1.6385x over previous
//
#include <hip/hip_runtime.h>

namespace {

constexpr int QN = 4;
constexpr int MR = 8192;   // B*S
constexpr int DD = 768;
constexpr int HH = 512;
constexpr int NN = 1024;
constexpr float DELTA = 0.008f;   // argmax tie-recheck threshold

typedef __attribute__((ext_vector_type(8))) __bf16 bf16x8;
typedef __attribute__((ext_vector_type(4))) __bf16 bf16x4;
typedef __attribute__((ext_vector_type(4))) float  f32x4;

#define GL2LDS(g, l) __builtin_amdgcn_global_load_lds( \
    (const __attribute__((address_space(1))) void*)(g), \
    (__attribute__((address_space(3))) void*)(l), 16, 0, 0)

// ------------- worklist counter init ------------------------------------
__global__ void zcnt(int* __restrict__ cnt)
{
    if (threadIdx.x < QN) cnt[threadIdx.x] = 0;
}

// ------------- transpose + fp32->bf16 weight conversion -----------------
// src: [batch][K][N] fp32  ->  dst: [batch][N][K] bf16
__global__ __launch_bounds__(256)
void wcvt(const float* __restrict__ src, __bf16* __restrict__ dst, int K, int N)
{
    __shared__ float tile[32][33];
    const size_t bo = (size_t)blockIdx.z * K * N;
    const int n0 = blockIdx.x * 32, k0 = blockIdx.y * 32;
    const int tx = threadIdx.x, ty = threadIdx.y;   // 32 x 8
    #pragma unroll
    for (int i = 0; i < 4; ++i)
        tile[ty + 8 * i][tx] = src[bo + (size_t)(k0 + ty + 8 * i) * N + n0 + tx];
    __syncthreads();
    #pragma unroll
    for (int i = 0; i < 4; ++i)
        dst[bo + (size_t)(n0 + ty + 8 * i) * K + k0 + tx] = (__bf16)tile[tx][ty + 8 * i];
}

// ------------- fp32 -> bf16 row-major copy (for x) ----------------------
__global__ __launch_bounds__(256)
void acvt(const float* __restrict__ src, __bf16* __restrict__ dst)
{
    const size_t i = ((size_t)blockIdx.x * 256 + threadIdx.x) * 8;
    float4 a = *(const float4*)(src + i);
    float4 b = *(const float4*)(src + i + 4);
    bf16x8 o;
    o[0] = (__bf16)a.x; o[1] = (__bf16)a.y; o[2] = (__bf16)a.z; o[3] = (__bf16)a.w;
    o[4] = (__bf16)b.x; o[5] = (__bf16)b.y; o[6] = (__bf16)b.z; o[7] = (__bf16)b.w;
    *(bf16x8*)(dst + i) = o;
}

// ------------- MFMA GEMM + BN(eval) + ReLU ------------------------------
template<int OUTBF>
__global__ __launch_bounds__(256)
void gemm_mfma(const __bf16* __restrict__ A, const __bf16* __restrict__ BT,
               const float* __restrict__ bias, const float* __restrict__ gam,
               const float* __restrict__ beta, const float* __restrict__ mean,
               const float* __restrict__ var,
               float* __restrict__ C32, __bf16* __restrict__ Cbf,
               int N_, int K_)
{
    __shared__ __bf16 smem[8192];          // As 4096 | Bs 4096 (16 KB)
    __bf16* As = smem;
    __bf16* Bs = smem + 4096;

    const int t   = threadIdx.x;
    const int bn0 = blockIdx.x * 128;
    const int bm0 = blockIdx.y * 128;
    const int l    = t & 63, w = t >> 6;
    const int lm   = l & 15, quad = l >> 4;
    const int mrow = (w & 1) * 64, ncol = (w >> 1) * 64;

    const int sA0 = t, sA1 = t + 256;
    const int mA0 = sA0 >> 2, qA0 = ((sA0 & 3) - (mA0 >> 1)) & 3;
    const int mA1 = sA1 >> 2, qA1 = ((sA1 & 3) - (mA1 >> 1)) & 3;
    const size_t gA0 = (size_t)(bm0 + mA0) * K_ + qA0 * 8;
    const size_t gA1 = (size_t)(bm0 + mA1) * K_ + qA1 * 8;
    const size_t gB0 = (size_t)(bn0 + mA0) * K_ + qA0 * 8;
    const size_t gB1 = (size_t)(bn0 + mA1) * K_ + qA1 * 8;

    f32x4 acc[4][4] = {};

    int aslot[4], bslot[4];
    #pragma unroll
    for (int i = 0; i < 4; ++i) {
        int m = mrow + i * 16 + lm;
        aslot[i] = m * 4 + ((quad + (m >> 1)) & 3);
        int n = ncol + i * 16 + lm;
        bslot[i] = n * 4 + ((quad + (n >> 1)) & 3);
    }

    for (int k0 = 0; k0 < K_; k0 += 32) {
        GL2LDS(A  + gA0 + k0, As + sA0 * 8);
        GL2LDS(A  + gA1 + k0, As + sA1 * 8);
        GL2LDS(BT + gB0 + k0, Bs + sA0 * 8);
        GL2LDS(BT + gB1 + k0, Bs + sA1 * 8);
        asm volatile("s_waitcnt vmcnt(0)" ::: "memory");
        __syncthreads();

        bf16x8 af[4], bfv[4];
        #pragma unroll
        for (int i = 0; i < 4; ++i) {
            af[i]  = *(const bf16x8*)(As + aslot[i] * 8);
            bfv[i] = *(const bf16x8*)(Bs + bslot[i] * 8);
        }
        #pragma unroll
        for (int mt = 0; mt < 4; ++mt)
            #pragma unroll
            for (int nt = 0; nt < 4; ++nt)
                acc[mt][nt] = __builtin_amdgcn_mfma_f32_16x16x32_bf16(
                    af[mt], bfv[nt], acc[mt][nt], 0, 0, 0);
        __syncthreads();
    }

    float sc[4], sh[4]; int cn[4];
    #pragma unroll
    for (int nt = 0; nt < 4; ++nt) {
        int c = bn0 + ncol + nt * 16 + lm;
        cn[nt] = c;
        float s = gam[c] * rsqrtf(var[c] + 1e-5f);
        sc[nt] = s;
        sh[nt] = (bias[c] - mean[c]) * s + beta[c];
    }
    #pragma unroll
    for (int mt = 0; mt < 4; ++mt) {
        int r0 = bm0 + mrow + mt * 16 + quad * 4;
        #pragma unroll
        for (int nt = 0; nt < 4; ++nt) {
            #pragma unroll
            for (int reg = 0; reg < 4; ++reg) {
                float v = fmaxf(0.f, fmaf(acc[mt][nt][reg], sc[nt], sh[nt]));
                size_t off = (size_t)(r0 + reg) * N_ + cn[nt];
                if (OUTBF) Cbf[off] = (__bf16)v;
                else       C32[off] = v;
            }
        }
    }
}

// ------------- per-row stats: softmax/entropy/latent/argmax + flag ------
__global__ __launch_bounds__(256)
void row_stats(const float* __restrict__ z, const float* __restrict__ gum,
               float* __restrict__ ent, float* __restrict__ lat,
               float* __restrict__ idxf, int* __restrict__ idxi,
               int* __restrict__ wl, int* __restrict__ cnt)
{
    __shared__ float sred[8];
    __shared__ int   sredi[4];
    __shared__ float stop1;
    __shared__ int   stop1i;

    const int r   = blockIdx.x;
    const int t   = threadIdx.x;
    const int wid = t >> 6;
    const bool l0 = (t & 63) == 0;

    const float4 z4 = ((const float4*)(z   + (size_t)r * NN))[t];
    const float4 g4 = ((const float4*)(gum + (size_t)r * NN))[t];

    // softmax stats
    float mx = fmaxf(fmaxf(z4.x, z4.y), fmaxf(z4.z, z4.w));
    #pragma unroll
    for (int o = 1; o < 64; o <<= 1) mx = fmaxf(mx, __shfl_xor(mx, o, 64));
    if (l0) sred[wid] = mx;
    __syncthreads();
    mx = fmaxf(fmaxf(sred[0], sred[1]), fmaxf(sred[2], sred[3]));

    float e0 = __expf(z4.x - mx), e1 = __expf(z4.y - mx);
    float e2 = __expf(z4.z - mx), e3 = __expf(z4.w - mx);
    float s = (e0 + e1) + (e2 + e3);
    #pragma unroll
    for (int o = 1; o < 64; o <<= 1) s += __shfl_xor(s, o, 64);
    if (l0) sred[4 + wid] = s;
    __syncthreads();
    s = (sred[4] + sred[5]) + (sred[6] + sred[7]);

    const float inv = 1.0f / s;
    const float q0 = e0 * inv, q1 = e1 * inv, q2 = e2 * inv, q3 = e3 * inv;

    float ep = q0 * __logf(q0 + 1e-10f) + q1 * __logf(q1 + 1e-10f)
             + q2 * __logf(q2 + 1e-10f) + q3 * __logf(q3 + 1e-10f);
    #pragma unroll
    for (int o = 1; o < 64; o <<= 1) ep += __shfl_xor(ep, o, 64);

    float4 l4;
    l4.x = q0 * __logf(q0 * 1024.f + 1e-10f);
    l4.y = q1 * __logf(q1 * 1024.f + 1e-10f);
    l4.z = q2 * __logf(q2 * 1024.f + 1e-10f);
    l4.w = q3 * __logf(q3 * 1024.f + 1e-10f);
    ((float4*)(lat + (size_t)r * NN))[t] = l4;

    // argmax(z+g) top-1
    const float y0 = z4.x + g4.x, y1 = z4.y + g4.y;
    const float y2 = z4.z + g4.z, y3 = z4.w + g4.w;
    float bv = y0; int bi = t * 4;
    if (y1 > bv) { bv = y1; bi = t * 4 + 1; }
    if (y2 > bv) { bv = y2; bi = t * 4 + 2; }
    if (y3 > bv) { bv = y3; bi = t * 4 + 3; }
    #pragma unroll
    for (int o = 1; o < 64; o <<= 1) {
        float ov = __shfl_xor(bv, o, 64);
        int   oi = __shfl_xor(bi, o, 64);
        if (ov > bv || (ov == bv && oi < bi)) { bv = ov; bi = oi; }
    }
    __syncthreads();
    if (l0) { sred[wid] = ep; sred[4 + wid] = bv; sredi[wid] = bi; }
    __syncthreads();
    if (t == 0) {
        ent[r] = -((sred[0] + sred[1]) + (sred[2] + sred[3]));
        float bbv = sred[4]; int bbi = sredi[0];
        #pragma unroll
        for (int ww = 1; ww < 4; ++ww)
            if (sred[4 + ww] > bbv || (sred[4 + ww] == bbv && sredi[ww] < bbi)) {
                bbv = sred[4 + ww]; bbi = sredi[ww];
            }
        stop1 = bbv; stop1i = bbi;
    }
    __syncthreads();
    const float t1v = stop1;
    const int   t1i = stop1i;

    // top-2 (excluding top-1) for tie detection
    float ex = -1e30f;
    if (t * 4 + 0 != t1i) ex = y0;
    if (t * 4 + 1 != t1i) ex = fmaxf(ex, y1);
    if (t * 4 + 2 != t1i) ex = fmaxf(ex, y2);
    if (t * 4 + 3 != t1i) ex = fmaxf(ex, y3);
    #pragma unroll
    for (int o = 1; o < 64; o <<= 1) ex = fmaxf(ex, __shfl_xor(ex, o, 64));
    __syncthreads();
    if (l0) sred[wid] = ex;
    __syncthreads();
    if (t == 0) {
        idxf[r] = (float)t1i;
        idxi[r] = t1i;
        float t2 = fmaxf(fmaxf(sred[0], sred[1]), fmaxf(sred[2], sred[3]));
        if (t1v - t2 < DELTA) {
            int p = atomicAdd(cnt, 1);
            wl[p] = r;
        }
    }
}

// ------------- fp32 recompute of flagged rows ---------------------------
__global__ __launch_bounds__(256)
void recheck(const int* __restrict__ wl, const int* __restrict__ cnt,
             const float* __restrict__ gum, const float* __restrict__ Ain,
             const float* __restrict__ W1, const float* __restrict__ b1,
             const float* __restrict__ g1, const float* __restrict__ be1,
             const float* __restrict__ m1, const float* __restrict__ v1,
             const float* __restrict__ W2, const float* __restrict__ b2,
             const float* __restrict__ g2, const float* __restrict__ be2,
             const float* __restrict__ m2, const float* __restrict__ v2,
             float* __restrict__ idxf, int* __restrict__ idxi)
{
    __shared__ float rowbuf[DD];
    __shared__ float hs[HH];
    __shared__ float sred[4];
    __shared__ int   sredi[4];

    const int t   = threadIdx.x;
    const int wid = t >> 6;
    const bool l0 = (t & 63) == 0;
    const int n = cnt[0];

    for (int w = blockIdx.x; w < n; w += gridDim.x) {
        const int r = wl[w];
        __syncthreads();   // protect rowbuf/hs from previous iteration
        if (t < 192)
            *(float4*)&rowbuf[t * 4] = *(const float4*)(Ain + (size_t)r * DD + t * 4);
        __syncthreads();

        // h = relu(bn(row @ W1 + b1)) — 2 outputs/thread, 16-deep load ILP
        #pragma unroll
        for (int jj = 0; jj < 2; ++jj) {
            const int j = t + jj * 256;
            float a0 = 0.f, a1 = 0.f, a2 = 0.f, a3 = 0.f;
            #pragma unroll 4
            for (int k = 0; k < DD; k += 4) {
                a0 = fmaf(rowbuf[k + 0], W1[(size_t)(k + 0) * HH + j], a0);
                a1 = fmaf(rowbuf[k + 1], W1[(size_t)(k + 1) * HH + j], a1);
                a2 = fmaf(rowbuf[k + 2], W1[(size_t)(k + 2) * HH + j], a2);
                a3 = fmaf(rowbuf[k + 3], W1[(size_t)(k + 3) * HH + j], a3);
            }
            float a = (a0 + a1) + (a2 + a3) + b1[j];
            float scl = g1[j] * rsqrtf(v1[j] + 1e-5f);
            hs[j] = fmaxf(0.f, (a - m1[j]) * scl + be1[j]);
        }
        __syncthreads();

        // z = relu(bn(h @ W2 + b2)); y = z + gumbel; block argmax
        float bv = -1e30f; int bi = 0;
        #pragma unroll
        for (int cc = 0; cc < 4; ++cc) {
            const int c = t + cc * 256;
            float a0 = 0.f, a1 = 0.f, a2 = 0.f, a3 = 0.f;
            #pragma unroll 4
            for (int j = 0; j < HH; j += 4) {
                a0 = fmaf(hs[j + 0], W2[(size_t)(j + 0) * NN + c], a0);
                a1 = fmaf(hs[j + 1], W2[(size_t)(j + 1) * NN + c], a1);
                a2 = fmaf(hs[j + 2], W2[(size_t)(j + 2) * NN + c], a2);
                a3 = fmaf(hs[j + 3], W2[(size_t)(j + 3) * NN + c], a3);
            }
            float a = (a0 + a1) + (a2 + a3) + b2[c];
            float scl = g2[c] * rsqrtf(v2[c] + 1e-5f);
            float zc  = fmaxf(0.f, (a - m2[c]) * scl + be2[c]);
            float y   = zc + gum[(size_t)r * NN + c];
            if (y > bv || (y == bv && c < bi)) { bv = y; bi = c; }
        }
        #pragma unroll
        for (int o = 1; o < 64; o <<= 1) {
            float ov = __shfl_xor(bv, o, 64);
            int   oi = __shfl_xor(bi, o, 64);
            if (ov > bv || (ov == bv && oi < bi)) { bv = ov; bi = oi; }
        }
        if (l0) { sred[wid] = bv; sredi[wid] = bi; }
        __syncthreads();
        if (t == 0) {
            float bbv = sred[0]; int bbi = sredi[0];
            #pragma unroll
            for (int ww = 1; ww < 4; ++ww)
                if (sred[ww] > bbv || (sred[ww] == bbv && sredi[ww] < bbi)) {
                    bbv = sred[ww]; bbi = sredi[ww];
                }
            idxf[r] = (float)bbi;
            idxi[r] = bbi;
        }
    }
}

// ------------- gather + residual / quantized_out update -----------------
__global__ __launch_bounds__(192)
void gather(const int* __restrict__ idxi, const float* __restrict__ cb,
            const float* __restrict__ Ain,
            float* __restrict__ res, float* __restrict__ qout,
            __bf16* __restrict__ res_bf, __bf16* __restrict__ qo_bf,
            int first, int last)
{
    const int r = blockIdx.x;
    const int t = threadIdx.x;     // 192 threads, 4 floats each
    const int ci = idxi[r];

    float4 c4 = *(const float4*)(cb + (size_t)ci * DD + t * 4);
    float4 rv, qv;
    if (first) {
        float4 xv = *(const float4*)(Ain + (size_t)r * DD + t * 4);
        rv.x = xv.x - c4.x; rv.y = xv.y - c4.y;
        rv.z = xv.z - c4.z; rv.w = xv.w - c4.w;
        qv = c4;
    } else {
        rv = *(const float4*)(res  + (size_t)r * DD + t * 4);
        qv = *(const float4*)(qout + (size_t)r * DD + t * 4);
        rv.x -= c4.x; rv.y -= c4.y; rv.z -= c4.z; rv.w -= c4.w;
        qv.x += c4.x; qv.y += c4.y; qv.z += c4.z; qv.w += c4.w;
    }
    *(float4*)(qout + (size_t)r * DD + t * 4) = qv;
    if (!last) {
        *(float4*)(res + (size_t)r * DD + t * 4) = rv;
        bf16x4 rb;
        rb[0] = (__bf16)rv.x; rb[1] = (__bf16)rv.y;
        rb[2] = (__bf16)rv.z; rb[3] = (__bf16)rv.w;
        *(bf16x4*)(res_bf + (size_t)r * DD + t * 4) = rb;
    } else {
        bf16x4 qb;
        qb[0] = (__bf16)qv.x; qb[1] = (__bf16)qv.y;
        qb[2] = (__bf16)qv.z; qb[3] = (__bf16)qv.w;
        *(bf16x4*)(qo_bf + (size_t)r * DD + t * 4) = qb;
    }
}

} // namespace

extern "C" void kernel_launch(void* const* d_in, const int* in_sizes, int n_in,
                              void* d_out, int out_size, void* d_ws, size_t ws_size,
                              hipStream_t stream)
{
    const float* x    = (const float*)d_in[0];
    const float* cb   = (const float*)d_in[1];
    const float* pW1  = (const float*)d_in[2];
    const float* pb1  = (const float*)d_in[3];
    const float* pg1  = (const float*)d_in[4];
    const float* pbe1 = (const float*)d_in[5];
    const float* pm1  = (const float*)d_in[6];
    const float* pv1  = (const float*)d_in[7];
    const float* pW2  = (const float*)d_in[8];
    const float* pb2  = (const float*)d_in[9];
    const float* pg2  = (const float*)d_in[10];
    const float* pbe2 = (const float*)d_in[11];
    const float* pm2  = (const float*)d_in[12];
    const float* pv2  = (const float*)d_in[13];
    const float* dW1  = (const float*)d_in[14];
    const float* db1  = (const float*)d_in[15];
    const float* dg1  = (const float*)d_in[16];
    const float* dbe1 = (const float*)d_in[17];
    const float* dm1  = (const float*)d_in[18];
    const float* dv1  = (const float*)d_in[19];
    const float* dW2  = (const float*)d_in[20];
    const float* db2  = (const float*)d_in[21];
    const float* dg2  = (const float*)d_in[22];
    const float* dbe2 = (const float*)d_in[23];
    const float* dm2  = (const float*)d_in[24];
    const float* dv2  = (const float*)d_in[25];
    const float* gum  = (const float*)d_in[26];

    // output layout (floats): xhat | entropies | latent | indices | zs
    float* out  = (float*)d_out;
    float* xhat = out;
    float* ent  = xhat + (size_t)MR * DD;
    float* lat  = ent  + (size_t)QN * MR;
    float* idxf = lat  + (size_t)QN * MR * NN;
    float* zs   = idxf + (size_t)QN * MR;

    // workspace layout
    char* wp = (char*)d_ws;
    float*  res   = (float*)wp;                 wp += (size_t)MR * DD * 4;
    float*  qo    = (float*)wp;                 wp += (size_t)MR * DD * 4;
    __bf16* Abf   = (__bf16*)wp;                wp += (size_t)MR * DD * 2;
    __bf16* hbf   = (__bf16*)wp;                wp += (size_t)MR * HH * 2;
    __bf16* qobf  = (__bf16*)wp;                wp += (size_t)MR * DD * 2;
    __bf16* h1bf  = (__bf16*)wp;                wp += (size_t)MR * 2 * DD * 2;
    __bf16* w1t   = (__bf16*)wp;                wp += (size_t)QN * DD * HH * 2;
    __bf16* w2t   = (__bf16*)wp;                wp += (size_t)QN * HH * NN * 2;
    __bf16* dw1t  = (__bf16*)wp;                wp += (size_t)DD * 2 * DD * 2;
    __bf16* dw2t  = (__bf16*)wp;                wp += (size_t)2 * DD * DD * 2;
    int*    idxi  = (int*)wp;                   wp += (size_t)QN * MR * 4;
    int*    wl    = (int*)wp;                   wp += (size_t)QN * MR * 4;
    int*    cnt   = (int*)wp;                   wp += 64;

    dim3 b256(256), bwc(32, 8);

    hipLaunchKernelGGL(zcnt, dim3(1), dim3(64), 0, stream, cnt);
    hipLaunchKernelGGL(wcvt, dim3(HH / 32, DD / 32, QN), bwc, 0, stream, pW1, w1t, DD, HH);
    hipLaunchKernelGGL(wcvt, dim3(NN / 32, HH / 32, QN), bwc, 0, stream, pW2, w2t, HH, NN);
    hipLaunchKernelGGL(wcvt, dim3(2 * DD / 32, DD / 32, 1), bwc, 0, stream, dW1, dw1t, DD, 2 * DD);
    hipLaunchKernelGGL(wcvt, dim3(DD / 32, 2 * DD / 32, 1), bwc, 0, stream, dW2, dw2t, 2 * DD, DD);
    hipLaunchKernelGGL(acvt, dim3((size_t)MR * DD / (8 * 256)), b256, 0, stream, x, Abf);

    for (int i = 0; i < QN; ++i) {
        hipLaunchKernelGGL((gemm_mfma<1>), dim3(HH / 128, MR / 128), b256, 0, stream,
            Abf, w1t + (size_t)i * DD * HH,
            pb1 + i * HH, pg1 + i * HH, pbe1 + i * HH, pm1 + i * HH, pv1 + i * HH,
            (float*)nullptr, hbf, HH, DD);
        float* z_i = zs + (size_t)i * MR * NN;
        hipLaunchKernelGGL((gemm_mfma<0>), dim3(NN / 128, MR / 128), b256, 0, stream,
            hbf, w2t + (size_t)i * HH * NN,
            pb2 + i * NN, pg2 + i * NN, pbe2 + i * NN, pm2 + i * NN, pv2 + i * NN,
            z_i, (__bf16*)nullptr, NN, HH);

        hipLaunchKernelGGL(row_stats, dim3(MR), b256, 0, stream,
            z_i, gum + (size_t)i * MR * NN,
            ent + (size_t)i * MR, lat + (size_t)i * MR * NN, idxf + (size_t)i * MR,
            idxi + (size_t)i * MR, wl + (size_t)i * MR, cnt + i);

        const float* Ain = (i == 0) ? x : res;
        hipLaunchKernelGGL(recheck, dim3(256), b256, 0, stream,
            wl + (size_t)i * MR, cnt + i, gum + (size_t)i * MR * NN, Ain,
            pW1 + (size_t)i * DD * HH, pb1 + i * HH, pg1 + i * HH, pbe1 + i * HH,
            pm1 + i * HH, pv1 + i * HH,
            pW2 + (size_t)i * HH * NN, pb2 + i * NN, pg2 + i * NN, pbe2 + i * NN,
            pm2 + i * NN, pv2 + i * NN,
            idxf + (size_t)i * MR, idxi + (size_t)i * MR);

        hipLaunchKernelGGL(gather, dim3(MR), dim3(192), 0, stream,
            idxi + (size_t)i * MR, cb + (size_t)i * NN * DD, Ain,
            res, qo, Abf, qobf, (int)(i == 0), (int)(i == QN - 1));
    }
    // decoder
    hipLaunchKernelGGL((gemm_mfma<1>), dim3(2 * DD / 128, MR / 128), b256, 0, stream,
        qobf, dw1t, db1, dg1, dbe1, dm1, dv1, (float*)nullptr, h1bf, 2 * DD, DD);
    hipLaunchKernelGGL((gemm_mfma<0>), dim3(DD / 128, MR / 128), b256, 0, stream,
        h1bf, dw2t, db2, dg2, dbe2, dm2, dv2, xhat, (__bf16*)nullptr, DD, 2 * DD);
}